// Round 1
// baseline (234.405 us; speedup 1.0000x reference)
//
#include <hip/hip_runtime.h>

// SparseAttention: B=8, M=N=4096, K=64, R=128 nnz/row (uniform CSR).
// One 256-thread block per (b, row). fp32 throughout.
#define Bc 8
#define Mc 4096
#define Nc 4096
#define Kc 64
#define Rc 128

__global__ __launch_bounds__(256) void sattn_kernel(
    const int* __restrict__ cols,    // [M*R], sorted within row
    const float* __restrict__ Q,     // [B,M,K]
    const float* __restrict__ Km,    // [B,N,K]
    const float* __restrict__ Vm,    // [B,N,K]
    float* __restrict__ out)         // [B,M,K]
{
    // b = blockIdx.x & 7: XCD-aware swizzle so each XCD's L2 mostly caches one batch's K/V.
    const int b   = blockIdx.x & 7;
    const int row = blockIdx.x >> 3;
    const int t   = threadIdx.x;

    __shared__ __align__(16) float s_q[Kc];
    __shared__ int   s_col[Rc];
    __shared__ float s_w[Rc];                    // logits, then exp(l-m)
    __shared__ __align__(16) float s_part[16][Kc];
    __shared__ float s_invden;

    // Stage Q row + column indices.
    if (t < Kc) s_q[t]   = Q[(((unsigned)b * Mc + row) << 6) + t];
    if (t < Rc) s_col[t] = cols[row * Rc + t];
    __syncthreads();

    // ---- SDDMM: logits[e] = <Q[b,row,:], K[b,col_e,:]> ----
    // 2 threads per edge; each sums 32 k's via 8 float4 loads.
    {
        const int e   = t >> 1;
        const int h   = t & 1;
        const int col = s_col[e];
        const float4* kp = (const float4*)(Km + (((unsigned)b * Nc + col) << 6) + h * 32);
        const float4* qp = (const float4*)(s_q + h * 32);
        float acc = 0.f;
        #pragma unroll
        for (int j = 0; j < 8; ++j) {
            float4 kv = kp[j];
            float4 qv = qp[j];
            acc = fmaf(qv.x, kv.x, acc);
            acc = fmaf(qv.y, kv.y, acc);
            acc = fmaf(qv.z, kv.z, acc);
            acc = fmaf(qv.w, kv.w, acc);
        }
        acc += __shfl_xor(acc, 1, 64);   // combine the two halves
        if (h == 0) s_w[e] = acc;
    }
    __syncthreads();

    // ---- Softmax over the 128 logits (wave 0 only) ----
    if (t < 64) {
        float l0 = s_w[t], l1 = s_w[t + 64];
        float m = fmaxf(l0, l1);
        #pragma unroll
        for (int o = 32; o; o >>= 1) m = fmaxf(m, __shfl_xor(m, o, 64));
        float e0 = __expf(l0 - m), e1 = __expf(l1 - m);
        s_w[t] = e0; s_w[t + 64] = e1;
        float s = e0 + e1;
        #pragma unroll
        for (int o = 32; o; o >>= 1) s += __shfl_xor(s, o, 64);
        if (t == 0) s_invden = 1.0f / s;
    }
    __syncthreads();

    // ---- SPMM: out[k] = (1/den) * sum_e w_e * V[b,col_e,k] ----
    // 16 edge-slots x 16 k-quads; each wave instruction reads 4 full V rows coalesced.
    {
        const int s  = t >> 4;
        const int qd = (t & 15) << 2;
        float4 acc = make_float4(0.f, 0.f, 0.f, 0.f);
        #pragma unroll
        for (int j = 0; j < 8; ++j) {
            const int e   = (j << 4) + s;
            const int col = s_col[e];
            const float w = s_w[e];
            const float4 vv = *(const float4*)(Vm + (((unsigned)b * Nc + col) << 6) + qd);
            acc.x = fmaf(w, vv.x, acc.x);
            acc.y = fmaf(w, vv.y, acc.y);
            acc.z = fmaf(w, vv.z, acc.z);
            acc.w = fmaf(w, vv.w, acc.w);
        }
        *(float4*)&s_part[s][qd] = acc;
    }
    __syncthreads();

    // Final cross-slot reduction + scale + store (coalesced 256 B).
    if (t < Kc) {
        float r = 0.f;
        #pragma unroll
        for (int s2 = 0; s2 < 16; ++s2) r += s_part[s2][t];
        out[(((unsigned)b * Mc + row) << 6) + t] = r * s_invden;
    }
}

extern "C" void kernel_launch(void* const* d_in, const int* in_sizes, int n_in,
                              void* d_out, int out_size, void* d_ws, size_t ws_size,
                              hipStream_t stream) {
    // setup_inputs order: 0 row_indices, 1 row_offsets, 2 column_indices,
    //                     3 q3d, 4 k3d, 5 v3d, 6 values(unused)
    const int*   cols = (const int*)d_in[2];
    const float* Q    = (const float*)d_in[3];
    const float* Km   = (const float*)d_in[4];
    const float* Vm   = (const float*)d_in[5];
    float* out = (float*)d_out;

    sattn_kernel<<<dim3(Bc * Mc), dim3(256), 0, stream>>>(cols, Q, Km, Vm, out);
}

// Round 2
// 193.057 us; speedup vs baseline: 1.2142x; 1.2142x over previous
//
#include <hip/hip_runtime.h>

// SparseAttention: B=8, M=N=4096, K=64, R=128 nnz/row (uniform CSR).
// One 256-thread block per (b, row). fp32 throughout.
// R1: SDDMM remapped to 16-lanes-per-edge coalesced loads (was 2 lanes/edge,
//     64 distinct cachelines per wave-instr -> L1 request-rate bound).
#define Bc 8
#define Mc 4096
#define Nc 4096
#define Kc 64
#define Rc 128

__global__ __launch_bounds__(256) void sattn_kernel(
    const int* __restrict__ cols,    // [M*R], sorted within row
    const float* __restrict__ Q,     // [B,M,K]
    const float* __restrict__ Km,    // [B,N,K]
    const float* __restrict__ Vm,    // [B,N,K]
    float* __restrict__ out)         // [B,M,K]
{
    // b = blockIdx.x & 7: XCD-aware swizzle so each XCD's L2 mostly caches one batch's K/V (~2 MB < 4 MB).
    const int b   = blockIdx.x & 7;
    const int row = blockIdx.x >> 3;
    const int t   = threadIdx.x;

    __shared__ __align__(16) float s_q[Kc];
    __shared__ int   s_col[Rc];
    __shared__ float s_w[Rc];                    // logits, then exp(l-m)
    __shared__ __align__(16) float s_part[16][Kc];
    __shared__ float s_invden;

    // Stage Q row + column indices.
    if (t < Kc) s_q[t]   = Q[(((unsigned)b * Mc + row) << 6) + t];
    if (t < Rc) s_col[t] = cols[row * Rc + t];
    __syncthreads();

    const int slot = t >> 4;          // 0..15 (4 slots per wave)
    const int qd   = (t & 15) << 2;   // float4 index into the 64-wide K dim

    // Q fragment for this lane (one ds_read_b128, reused across all 8 passes).
    const float4 qv = *(const float4*)(s_q + qd);

    // ---- SDDMM: logits[e] = <Q[b,row,:], K[b,col_e,:]> ----
    // 16 lanes per edge, each lane one float4 -> 4 rows x 256B contiguous per wave-instr.
    #pragma unroll
    for (int p = 0; p < 8; ++p) {
        const int e   = (p << 4) + slot;
        const int col = s_col[e];
        const float4 kv = *(const float4*)(Km + (((unsigned)b * Nc + col) << 6) + qd);
        float acc;
        acc = qv.x * kv.x;
        acc = fmaf(qv.y, kv.y, acc);
        acc = fmaf(qv.z, kv.z, acc);
        acc = fmaf(qv.w, kv.w, acc);
        // Reduce across the 16 lanes of this group (contiguous lanes, xor stays in-group).
        acc += __shfl_xor(acc, 1, 64);
        acc += __shfl_xor(acc, 2, 64);
        acc += __shfl_xor(acc, 4, 64);
        acc += __shfl_xor(acc, 8, 64);
        if ((t & 15) == 0) s_w[e] = acc;
    }
    __syncthreads();

    // ---- Softmax over the 128 logits (wave 0 only) ----
    if (t < 64) {
        float l0 = s_w[t], l1 = s_w[t + 64];
        float m = fmaxf(l0, l1);
        #pragma unroll
        for (int o = 32; o; o >>= 1) m = fmaxf(m, __shfl_xor(m, o, 64));
        float e0 = __expf(l0 - m), e1 = __expf(l1 - m);
        s_w[t] = e0; s_w[t + 64] = e1;
        float s = e0 + e1;
        #pragma unroll
        for (int o = 32; o; o >>= 1) s += __shfl_xor(s, o, 64);
        if (t == 0) s_invden = 1.0f / s;
    }
    __syncthreads();

    // ---- SPMM: out[k] = (1/den) * sum_e w_e * V[b,col_e,k] ----
    // Same 16-lane-per-row mapping: 4 rows x 256B contiguous per wave-instr.
    {
        float4 acc = make_float4(0.f, 0.f, 0.f, 0.f);
        #pragma unroll
        for (int p = 0; p < 8; ++p) {
            const int e   = (p << 4) + slot;
            const int col = s_col[e];
            const float w = s_w[e];
            const float4 vv = *(const float4*)(Vm + (((unsigned)b * Nc + col) << 6) + qd);
            acc.x = fmaf(w, vv.x, acc.x);
            acc.y = fmaf(w, vv.y, acc.y);
            acc.z = fmaf(w, vv.z, acc.z);
            acc.w = fmaf(w, vv.w, acc.w);
        }
        *(float4*)&s_part[slot][qd] = acc;
    }
    __syncthreads();

    // Final cross-slot reduction + scale + store (coalesced 256 B).
    if (t < Kc) {
        float r = 0.f;
        #pragma unroll
        for (int s2 = 0; s2 < 16; ++s2) r += s_part[s2][t];
        out[(((unsigned)b * Mc + row) << 6) + t] = r * s_invden;
    }
}

extern "C" void kernel_launch(void* const* d_in, const int* in_sizes, int n_in,
                              void* d_out, int out_size, void* d_ws, size_t ws_size,
                              hipStream_t stream) {
    // setup_inputs order: 0 row_indices, 1 row_offsets, 2 column_indices,
    //                     3 q3d, 4 k3d, 5 v3d, 6 values(unused)
    const int*   cols = (const int*)d_in[2];
    const float* Q    = (const float*)d_in[3];
    const float* Km   = (const float*)d_in[4];
    const float* Vm   = (const float*)d_in[5];
    float* out = (float*)d_out;

    sattn_kernel<<<dim3(Bc * Mc), dim3(256), 0, stream>>>(cols, Q, Km, Vm, out);
}

// Round 3
// 143.818 us; speedup vs baseline: 1.6299x; 1.3424x over previous
//
#include <hip/hip_runtime.h>

// SparseAttention: B=8, M=N=4096, K=64, R=128 nnz/row (uniform CSR).
// R2 was L2-random-gather-BW bound (66 GB/s/CU, VALUBusy 32%).
// R3: stage K,V as fp16 in d_ws -> halve gather bytes; fdot2 SDDMM;
//     V prefetch before softmax barrier; per-batch K+V now fits XCD L2.
#define Bc 8
#define Mc 4096
#define Nc 4096
#define Kc 64
#define Rc 128

typedef _Float16 h16;
typedef h16 h16x2 __attribute__((ext_vector_type(2)));
typedef h16 h16x4 __attribute__((ext_vector_type(4)));
typedef h16 h16x8 __attribute__((ext_vector_type(8)));

// fp32 -> fp16 staging for K and V (read 16.8 MB, write 8.4 MB; ~5 us).
__global__ __launch_bounds__(256) void cvt_fp16(
    const float4* __restrict__ K4, const float4* __restrict__ V4,
    h16x4* __restrict__ Kh4, h16x4* __restrict__ Vh4)
{
    const int n4 = Bc * Nc * Kc / 4;  // 524288 float4-groups per tensor
    int i = blockIdx.x * 256 + threadIdx.x;
    const float4* src; h16x4* dst; int idx;
    if (i < n4) { src = K4; dst = Kh4; idx = i; }
    else        { src = V4; dst = Vh4; idx = i - n4; }
    float4 v = src[idx];
    h16x4 o = { (h16)v.x, (h16)v.y, (h16)v.z, (h16)v.w };
    dst[idx] = o;
}

__global__ __launch_bounds__(256) void sattn_kernel(
    const int* __restrict__ cols,    // [M*R], sorted within row
    const float* __restrict__ Q,     // [B,M,K] fp32
    const h16* __restrict__ Kh,      // [B,N,K] fp16 (staged)
    const h16* __restrict__ Vh,      // [B,N,K] fp16 (staged)
    float* __restrict__ out)         // [B,M,K] fp32
{
    const int b   = blockIdx.x & 7;   // XCD swizzle: one batch per XCD's L2 (K+V fp16 = 2 MiB < 4 MiB)
    const int row = blockIdx.x >> 3;
    const int t   = threadIdx.x;
    const int g   = t >> 3;           // group 0..31 (8 lanes per edge)
    const int ln  = t & 7;            // lane-in-group; handles k = ln*8 .. ln*8+7

    __shared__ float s_w[Rc];                     // logits -> exp(l-m)
    __shared__ __align__(16) float s_part[32][Kc]; // 8 KB partials
    __shared__ __align__(16) float s_red[4][Kc];   // 1 KB stage-2
    __shared__ float s_invden;

    // Per-thread columns for its 4 edges (8 lanes/group read same addr -> L1 broadcast).
    int col4[4];
    #pragma unroll
    for (int p = 0; p < 4; ++p) col4[p] = cols[row * Rc + p * 32 + g];

    // Q fragment: 8 floats at k = ln*8 (whole wave reads same 256B row -> L1-hot), cvt to fp16.
    const float4* qp = (const float4*)(Q + (((unsigned)b * Mc + row) << 6) + ln * 8);
    float4 q0 = qp[0], q1 = qp[1];
    h16x2 qh[4];
    qh[0] = h16x2{ (h16)q0.x, (h16)q0.y };
    qh[1] = h16x2{ (h16)q0.z, (h16)q0.w };
    qh[2] = h16x2{ (h16)q1.x, (h16)q1.y };
    qh[3] = h16x2{ (h16)q1.z, (h16)q1.w };

    // ---- SDDMM: preload all 4 K fragments (16B each, coalesced: 8 rows x 128B per wave-instr) ----
    h16x8 kv[4];
    #pragma unroll
    for (int p = 0; p < 4; ++p)
        kv[p] = *(const h16x8*)(Kh + ((((unsigned)b * Nc + col4[p]) << 6) + ln * 8));

    #pragma unroll
    for (int p = 0; p < 4; ++p) {
        float acc = 0.f;
        #pragma unroll
        for (int j = 0; j < 4; ++j) {
            h16x2 kj = { kv[p][2 * j], kv[p][2 * j + 1] };
#if defined(__has_builtin)
#if __has_builtin(__builtin_amdgcn_fdot2)
            acc = __builtin_amdgcn_fdot2(qh[j], kj, acc, false);
#else
            acc += (float)qh[j].x * (float)kj.x + (float)qh[j].y * (float)kj.y;
#endif
#else
            acc += (float)qh[j].x * (float)kj.x + (float)qh[j].y * (float)kj.y;
#endif
        }
        // Reduce across the 8 lanes of the group.
        acc += __shfl_xor(acc, 1, 64);
        acc += __shfl_xor(acc, 2, 64);
        acc += __shfl_xor(acc, 4, 64);
        if (ln == 0) s_w[p * 32 + g] = acc;
    }

    // ---- V prefetch: independent of softmax; overlaps the barrier's vmcnt drain. ----
    h16x8 vv[4];
    #pragma unroll
    for (int p = 0; p < 4; ++p)
        vv[p] = *(const h16x8*)(Vh + ((((unsigned)b * Nc + col4[p]) << 6) + ln * 8));

    __syncthreads();

    // ---- Softmax over the 128 logits (wave 0) ----
    if (t < 64) {
        float l0 = s_w[t], l1 = s_w[t + 64];
        float m = fmaxf(l0, l1);
        #pragma unroll
        for (int o = 32; o; o >>= 1) m = fmaxf(m, __shfl_xor(m, o, 64));
        float e0 = __expf(l0 - m), e1 = __expf(l1 - m);
        s_w[t] = e0; s_w[t + 64] = e1;
        float s = e0 + e1;
        #pragma unroll
        for (int o = 32; o; o >>= 1) s += __shfl_xor(s, o, 64);
        if (t == 0) s_invden = 1.0f / s;
    }
    __syncthreads();

    // ---- SPMM: acc8[k] += w_e * V[col_e, k] over this group's 4 edges ----
    float acc8[8] = {0.f,0.f,0.f,0.f,0.f,0.f,0.f,0.f};
    #pragma unroll
    for (int p = 0; p < 4; ++p) {
        const float w = s_w[p * 32 + g];
        #pragma unroll
        for (int j = 0; j < 8; ++j)
            acc8[j] = fmaf((float)vv[p][j], w, acc8[j]);
    }
    *(float4*)&s_part[g][ln * 8]     = *(float4*)&acc8[0];
    *(float4*)&s_part[g][ln * 8 + 4] = *(float4*)&acc8[4];
    __syncthreads();

    // ---- Two-stage cross-group reduction (all 256 threads) ----
    {
        const int k = t & 63, qq = t >> 6;
        float r = 0.f;
        #pragma unroll
        for (int j = 0; j < 8; ++j) r += s_part[qq * 8 + j][k];
        s_red[qq][k] = r;
    }
    __syncthreads();
    if (t < 64) {
        float r = (s_red[0][t] + s_red[1][t]) + (s_red[2][t] + s_red[3][t]);
        out[(((unsigned)b * Mc + row) << 6) + t] = r * s_invden;
    }
}

extern "C" void kernel_launch(void* const* d_in, const int* in_sizes, int n_in,
                              void* d_out, int out_size, void* d_ws, size_t ws_size,
                              hipStream_t stream) {
    // inputs: 0 row_indices, 1 row_offsets, 2 column_indices, 3 q3d, 4 k3d, 5 v3d, 6 values
    const int*   cols = (const int*)d_in[2];
    const float* Q    = (const float*)d_in[3];
    const float* Km   = (const float*)d_in[4];
    const float* Vm   = (const float*)d_in[5];
    float* out = (float*)d_out;

    h16* Kh = (h16*)d_ws;
    h16* Vh = Kh + (size_t)Bc * Nc * Kc;   // 4.19 MB each, 8.39 MB total in d_ws

    const int n4 = Bc * Nc * Kc / 4;       // 524288 per tensor
    cvt_fp16<<<dim3(2 * n4 / 256), dim3(256), 0, stream>>>(
        (const float4*)Km, (const float4*)Vm, (h16x4*)Kh, (h16x4*)Vh);
    sattn_kernel<<<dim3(Bc * Mc), dim3(256), 0, stream>>>(cols, Q, Kh, Vh, out);
}